// Round 2
// 721.545 us; speedup vs baseline: 1.2364x; 1.2364x over previous
//
#include <hip/hip_runtime.h>
#include <hip/hip_bf16.h>
#include <stdint.h>

#define N_DIM 8192
#define H_DIM 1024
#define E_DIM 8192
#define PENALTY_F 10.0f
#define WSCALE 16.0f      // weights and H outputs stored *16 in e4m3
#define INV_WSCALE 0.0625f

typedef unsigned short u16;
typedef unsigned char u8;
typedef unsigned int u32;
typedef __attribute__((ext_vector_type(4))) float f32x4;
typedef __attribute__((ext_vector_type(2))) float f32x2;
typedef __attribute__((ext_vector_type(4))) int i32x4;
typedef __attribute__((ext_vector_type(8))) int i32x8;

// pack 4 floats -> 4 e4m3 bytes (OCP on gfx950)
__device__ __forceinline__ u32 pack4_fp8(float a, float b, float c, float d) {
  u32 p = __builtin_amdgcn_cvt_pk_fp8_f32(a, b, 0, false);
  p = __builtin_amdgcn_cvt_pk_fp8_f32(c, d, p, true);
  return p;
}
__device__ __forceinline__ f32x2 unpk_lo(u32 v) {
  return __builtin_amdgcn_cvt_pk_f32_fp8(v, false);
}
__device__ __forceinline__ f32x2 unpk_hi(u32 v) {
  return __builtin_amdgcn_cvt_pk_f32_fp8(v, true);
}

#define GLD16(ldsptr, gptr)                                                     \
  __builtin_amdgcn_global_load_lds(                                             \
      (__attribute__((address_space(1))) void*)(gptr),                          \
      (__attribute__((address_space(3))) void*)(ldsptr), 16, 0, 0)

// ---------------------------------------------------------------------------
// reduce helpers
// ---------------------------------------------------------------------------
__device__ __forceinline__ float wave_red(float v) {
  for (int o = 32; o; o >>= 1) v += __shfl_down(v, o, 64);
  return v;
}

__device__ __forceinline__ float block_reduce1(float v) {
  __shared__ float buf[4];
  v = wave_red(v);
  int lane = threadIdx.x & 63, w = threadIdx.x >> 6;
  if (lane == 0) buf[w] = v;
  __syncthreads();
  float r = 0.f;
  if (threadIdx.x == 0) r = buf[0] + buf[1] + buf[2] + buf[3];
  return r;  // valid on thread 0
}

// ---------------------------------------------------------------------------
// fp32 -> fp8 (A only; scale 1)
// ---------------------------------------------------------------------------
__global__ void convert_f32_fp8(const float* __restrict__ in,
                                u8* __restrict__ out, int n4, float scale) {
  int i = blockIdx.x * blockDim.x + threadIdx.x;
  if (i < n4) {
    float4 v = ((const float4*)in)[i];
    ((u32*)out)[i] =
        pack4_fp8(v.x * scale, v.y * scale, v.z * scale, v.w * scale);
  }
}

// ---------------------------------------------------------------------------
// fused: W1/W2 fp32->fp8 (*WSCALE) + row norms + b1/b2 norms, all * E.
// grid: [0,1024) W1 rows (block/row); [1024,3072) W2 4 rows/block (wave/row);
//       3072 -> b1 ; 3073 -> b2.
// ---------------------------------------------------------------------------
__global__ void prep_w(const float* __restrict__ W1,
                       const float* __restrict__ W2,
                       const float* __restrict__ b1,
                       const float* __restrict__ b2, u8* __restrict__ W1_8,
                       u8* __restrict__ W2_8, float* __restrict__ out) {
  const int blk = blockIdx.x;
  if (blk < H_DIM) {  // W1 row: 8192 floats
    const float4* row = (const float4*)(W1 + (size_t)blk * N_DIM);
    u32* orow = (u32*)(W1_8 + (size_t)blk * N_DIM);
    float s = 0.f;
#pragma unroll
    for (int t = 0; t < 8; ++t) {
      int i = threadIdx.x + t * 256;
      float4 v = row[i];
      s += v.x * v.x + v.y * v.y + v.z * v.z + v.w * v.w;
      orow[i] = pack4_fp8(v.x * WSCALE, v.y * WSCALE, v.z * WSCALE,
                          v.w * WSCALE);
    }
    s = block_reduce1(s);
    if (threadIdx.x == 0) atomicAdd(out, sqrtf(s) * (float)E_DIM);
  } else if (blk < H_DIM + N_DIM / 4) {  // W2: 4 rows/block, 1024 floats each
    __shared__ float buf[4];
    const int wave = threadIdx.x >> 6, lane = threadIdx.x & 63;
    const int r = (blk - H_DIM) * 4 + wave;
    const float4* row = (const float4*)(W2 + (size_t)r * H_DIM);
    u32* orow = (u32*)(W2_8 + (size_t)r * H_DIM);
    float s = 0.f;
#pragma unroll
    for (int t = 0; t < 4; ++t) {
      int i = lane + t * 64;
      float4 v = row[i];
      s += v.x * v.x + v.y * v.y + v.z * v.z + v.w * v.w;
      orow[i] = pack4_fp8(v.x * WSCALE, v.y * WSCALE, v.z * WSCALE,
                          v.w * WSCALE);
    }
    s = wave_red(s);
    if (lane == 0) buf[wave] = sqrtf(s);
    __syncthreads();
    if (threadIdx.x == 0)
      atomicAdd(out, (buf[0] + buf[1] + buf[2] + buf[3]) * (float)E_DIM);
  } else if (blk == H_DIM + N_DIM / 4) {  // ||b1||, 1024 floats
    const float4* row = (const float4*)b1;
    float4 v = row[threadIdx.x];
    float s = v.x * v.x + v.y * v.y + v.z * v.z + v.w * v.w;
    s = block_reduce1(s);
    if (threadIdx.x == 0) atomicAdd(out, sqrtf(s) * (float)E_DIM);
  } else {  // ||b2||, 8192 floats
    const float4* row = (const float4*)b2;
    float s = 0.f;
#pragma unroll
    for (int t = 0; t < 8; ++t) {
      float4 v = row[threadIdx.x + t * 256];
      s += v.x * v.x + v.y * v.y + v.z * v.z + v.w * v.w;
    }
    s = block_reduce1(s);
    if (threadIdx.x == 0) atomicAdd(out, sqrtf(s) * (float)E_DIM);
  }
}

// ---------------------------------------------------------------------------
// MX-scaled fp8 GEMM: C = fp8( WSCALE * sigmoid( invScale*(A B^T) + bias ) )
// A[M][K], B[Nd][K] e4m3 row-major, K % 128 == 0.
// 128x128 tile, BKB=128 fp8/K-iter, 4 waves 2x2, 64x64 per wave as 4x4 MFMA
// 16x16x128 f8f6f4 (scales = 1.0). OPERANDS SWAPPED (mfma(B,A)): lane then
// holds ONE C-row (m15) and 4 CONSECUTIVE C-cols (quad*4+i) per acc -> the
// epilogue packs 4 adjacent fp8 bytes into one u32 store (16 dword stores vs
// 64 byte stores per thread).
// ---------------------------------------------------------------------------
#define BM 128
#define BN 128
#define BKB 128

__global__ __launch_bounds__(256) void gemm_fp8_sigmoid(
    const u8* __restrict__ Ag,    // [M][K]
    const u8* __restrict__ Bg,    // [Nd][K]
    const float* __restrict__ bias,
    u8* __restrict__ Cg,          // [M][Nd] e4m3, value*WSCALE
    float invScale, int K, int Nd) {
  __shared__ __align__(16) u8 Xs[BM * BKB];
  __shared__ __align__(16) u8 Ws[BN * BKB];

  const int tid = threadIdx.x;
  const int wave = tid >> 6, lane = tid & 63;
  const int wr = wave >> 1, wc = wave & 1;
  const size_t rowBase = (size_t)blockIdx.y * BM;
  const size_t colBase = (size_t)blockIdx.x * BN;

  f32x4 acc[4][4] = {};

  const int i8 = lane >> 3;  // row within 8-row staging group
  const int c8 = lane & 7;   // LDS 16-B slot
  const int sw = c8 ^ i8;    // swizzled global 16-B unit

  const int quad = lane >> 4;
  const int m15 = lane & 15;

  for (int k0 = 0; k0 < K; k0 += BKB) {
#pragma unroll
    for (int j = 0; j < 4; ++j) {
      const int r0 = (wave * 4 + j) * 8;
      const u8* gx = Ag + (rowBase + r0 + i8) * (size_t)K + (k0 + sw * 16);
      GLD16(&Xs[r0 * BKB], gx);
      const u8* gw = Bg + (colBase + r0 + i8) * (size_t)K + (k0 + sw * 16);
      GLD16(&Ws[r0 * BKB], gw);
    }
    __syncthreads();

    i32x8 af[4], bfr[4];
#pragma unroll
    for (int t = 0; t < 4; ++t) {
      const int m = wr * 64 + t * 16 + m15;
      i32x4 alo = *(const i32x4*)&Xs[m * BKB + ((2 * quad) ^ (m & 7)) * 16];
      i32x4 ahi = *(const i32x4*)&Xs[m * BKB + ((2 * quad + 1) ^ (m & 7)) * 16];
      af[t] = __builtin_shufflevector(alo, ahi, 0, 1, 2, 3, 4, 5, 6, 7);
      const int n = wc * 64 + t * 16 + m15;
      i32x4 blo = *(const i32x4*)&Ws[n * BKB + ((2 * quad) ^ (n & 7)) * 16];
      i32x4 bhi = *(const i32x4*)&Ws[n * BKB + ((2 * quad + 1) ^ (n & 7)) * 16];
      bfr[t] = __builtin_shufflevector(blo, bhi, 0, 1, 2, 3, 4, 5, 6, 7);
    }
#pragma unroll
    for (int mt = 0; mt < 4; ++mt)
#pragma unroll
      for (int nt = 0; nt < 4; ++nt)
        acc[mt][nt] = __builtin_amdgcn_mfma_scale_f32_16x16x128_f8f6f4(
            bfr[nt], af[mt], acc[mt][nt], 0, 0,
            0, 0x7F7F7F7F, 0, 0x7F7F7F7F);  // SWAPPED: D[n][m] layout
    __syncthreads();
  }

  // epilogue: lane owns C row (mt*16+m15), cols nt*16+quad*4+{0..3}
  f32x4 bv4[4];
#pragma unroll
  for (int nt = 0; nt < 4; ++nt)
    bv4[nt] = *(const f32x4*)&bias[colBase + wc * 64 + nt * 16 + quad * 4];
#pragma unroll
  for (int mt = 0; mt < 4; ++mt) {
    const size_t grow = rowBase + wr * 64 + mt * 16 + m15;
    u32* crow = (u32*)(Cg + grow * (size_t)Nd + colBase + wc * 64);
#pragma unroll
    for (int nt = 0; nt < 4; ++nt) {
      float v[4];
#pragma unroll
      for (int i = 0; i < 4; ++i) {
        float x = acc[mt][nt][i] * invScale + bv4[nt][i];
        v[i] = WSCALE / (1.0f + __expf(-x));
      }
      crow[nt * 4 + quad] = pack4_fp8(v[0], v[1], v[2], v[3]);
    }
  }
}

// ---------------------------------------------------------------------------
// loss_1 layer-1: one WAVE per edge (4 edges/block), exactly one dwordx4 per
// lane per row. Early-exit waves whose label is 0. One atomic per block.
// ---------------------------------------------------------------------------
__global__ void edge_loss_h(const u8* __restrict__ H1,
                            const int* __restrict__ edges,
                            const int* __restrict__ labels,
                            float* __restrict__ out) {
  __shared__ float buf[4];
  const int wave = threadIdx.x >> 6, lane = threadIdx.x & 63;
  const int e = blockIdx.x * 4 + wave;
  float r = 0.f;
  if (labels[e] != 0) {
    const int ni = edges[e * 2], nj = edges[e * 2 + 1];
    const i32x4 a = ((const i32x4*)(H1 + (size_t)ni * H_DIM))[lane];
    const i32x4 b = ((const i32x4*)(H1 + (size_t)nj * H_DIM))[lane];
    float s = 0.f;
#pragma unroll
    for (int j = 0; j < 4; ++j) {
      f32x2 al = unpk_lo((u32)a[j]), ah = unpk_hi((u32)a[j]);
      f32x2 bl = unpk_lo((u32)b[j]), bh = unpk_hi((u32)b[j]);
      float d0 = al.x - bl.x, d1 = al.y - bl.y;
      float d2 = ah.x - bh.x, d3 = ah.y - bh.y;
      s += d0 * d0 + d1 * d1 + d2 * d2 + d3 * d3;
    }
    s = wave_red(s);
    r = sqrtf(s) * INV_WSCALE;
  }
  if (lane == 0) buf[wave] = r;
  __syncthreads();
  if (threadIdx.x == 0) atomicAdd(out, buf[0] + buf[1] + buf[2] + buf[3]);
}

// ---------------------------------------------------------------------------
// loss_1 layer-2 + loss_2: one WAVE per edge, dwordx4 loads (8/lane/array).
// ---------------------------------------------------------------------------
__global__ void edge_loss_final(const u8* __restrict__ H2,
                                const u8* __restrict__ A8,
                                const int* __restrict__ edges,
                                const int* __restrict__ labels,
                                float* __restrict__ out) {
  __shared__ float buf[4];
  const int wave = threadIdx.x >> 6, lane = threadIdx.x & 63;
  const int e = blockIdx.x * 4 + wave;
  const int ni = edges[e * 2], nj = edges[e * 2 + 1];
  const i32x4* hi = (const i32x4*)(H2 + (size_t)ni * N_DIM);
  const i32x4* hj = (const i32x4*)(H2 + (size_t)nj * N_DIM);
  const i32x4* xi = (const i32x4*)(A8 + (size_t)ni * N_DIM);
  const i32x4* xj = (const i32x4*)(A8 + (size_t)nj * N_DIM);
  float s12 = 0.f, si = 0.f, sj = 0.f;
#pragma unroll 2
  for (int t = 0; t < 8; ++t) {
    const int idx = lane + t * 64;
    i32x4 a = hi[idx], b = hj[idx], x = xi[idx], y = xj[idx];
#pragma unroll
    for (int j = 0; j < 4; ++j) {
      f32x2 al = unpk_lo((u32)a[j]), ah = unpk_hi((u32)a[j]);
      f32x2 bl = unpk_lo((u32)b[j]), bh = unpk_hi((u32)b[j]);
      f32x2 xl = unpk_lo((u32)x[j]), xh = unpk_hi((u32)x[j]);
      f32x2 yl = unpk_lo((u32)y[j]), yh = unpk_hi((u32)y[j]);
      float d;
      d = al.x - bl.x; s12 += d * d;
      d = al.y - bl.y; s12 += d * d;
      d = ah.x - bh.x; s12 += d * d;
      d = ah.y - bh.y; s12 += d * d;
      d = WSCALE * xl.x - al.x; si += d * d;
      d = WSCALE * xl.y - al.y; si += d * d;
      d = WSCALE * xh.x - ah.x; si += d * d;
      d = WSCALE * xh.y - ah.y; si += d * d;
      d = WSCALE * yl.x - bl.x; sj += d * d;
      d = WSCALE * yl.y - bl.y; sj += d * d;
      d = WSCALE * yh.x - bh.x; sj += d * d;
      d = WSCALE * yh.y - bh.y; sj += d * d;
    }
  }
  for (int o = 32; o; o >>= 1) {
    s12 += __shfl_down(s12, o, 64);
    si += __shfl_down(si, o, 64);
    sj += __shfl_down(sj, o, 64);
  }
  if (lane == 0) {
    float lab = (labels[e] != 0) ? 1.f : 0.f;
    float fac = (labels[e] != 0) ? PENALTY_F : 1.f;
    buf[wave] = (lab * sqrtf(s12) + fac * (sqrtf(si) + sqrtf(sj))) * INV_WSCALE;
  }
  __syncthreads();
  if (threadIdx.x == 0) atomicAdd(out, buf[0] + buf[1] + buf[2] + buf[3]);
}

// ---------------------------------------------------------------------------
extern "C" void kernel_launch(void* const* d_in, const int* in_sizes, int n_in,
                              void* d_out, int out_size, void* d_ws,
                              size_t ws_size, hipStream_t stream) {
  const float* A = (const float*)d_in[0];
  const float* W1 = (const float*)d_in[1];
  const float* b1 = (const float*)d_in[2];
  const float* W2 = (const float*)d_in[3];
  const float* b2 = (const float*)d_in[4];
  const int* edges = (const int*)d_in[5];
  const int* labels = (const int*)d_in[6];
  float* out = (float*)d_out;

  // workspace layout (bytes), total ~152 MB
  char* ws = (char*)d_ws;
  u8* A8   = (u8*)(ws);                       // N x N fp8     64 MB
  u8* H1_8 = (u8*)(ws + 67108864ull);         // N x H fp8      8 MB
  u8* H2_8 = (u8*)(ws + 75497472ull);         // N x N fp8     64 MB
  u8* W1_8 = (u8*)(ws + 142606336ull);        // H x N fp8      8 MB
  u8* W2_8 = (u8*)(ws + 150994944ull);        // N x H fp8      8 MB

  hipMemsetAsync(out, 0, sizeof(float), stream);

  // A -> fp8 (scale 1)
  convert_f32_fp8<<<(N_DIM * N_DIM / 4 + 255) / 256, 256, 0, stream>>>(
      A, A8, N_DIM * N_DIM / 4, 1.0f);

  // W1/W2 convert (*16) fused with row norms; b1/b2 norms; all *E, exact fp32
  prep_w<<<H_DIM + N_DIM / 4 + 2, 256, 0, stream>>>(W1, W2, b1, b2, W1_8,
                                                    W2_8, out);

  // layer 1 (per node): H1 = sigmoid(A @ W1^T + b1)   [N x H]
  gemm_fp8_sigmoid<<<dim3(H_DIM / BN, N_DIM / BM), 256, 0, stream>>>(
      A8, W1_8, b1, H1_8, INV_WSCALE, N_DIM, H_DIM);
  edge_loss_h<<<E_DIM / 4, 256, 0, stream>>>(H1_8, edges, labels, out);

  // layer 2 (per node): H2 = sigmoid(H1 @ W2^T + b2)  [N x N]
  gemm_fp8_sigmoid<<<dim3(N_DIM / BN, N_DIM / BM), 256, 0, stream>>>(
      H1_8, W2_8, b2, H2_8, INV_WSCALE * INV_WSCALE, H_DIM, N_DIM);
  edge_loss_final<<<E_DIM / 4, 256, 0, stream>>>(H2_8, A8, edges, labels, out);
}

// Round 3
// 704.417 us; speedup vs baseline: 1.2664x; 1.0243x over previous
//
#include <hip/hip_runtime.h>
#include <hip/hip_bf16.h>
#include <stdint.h>

#define N_DIM 8192
#define H_DIM 1024
#define E_DIM 8192
#define PENALTY_F 10.0f
#define WSCALE 16.0f      // weights and H outputs stored *16 in e4m3
#define INV_WSCALE 0.0625f

typedef unsigned short u16;
typedef unsigned char u8;
typedef unsigned int u32;
typedef __attribute__((ext_vector_type(4))) float f32x4;
typedef __attribute__((ext_vector_type(2))) float f32x2;
typedef __attribute__((ext_vector_type(4))) int i32x4;
typedef __attribute__((ext_vector_type(8))) int i32x8;

// pack 4 floats -> 4 e4m3 bytes (OCP on gfx950)
__device__ __forceinline__ u32 pack4_fp8(float a, float b, float c, float d) {
  u32 p = __builtin_amdgcn_cvt_pk_fp8_f32(a, b, 0, false);
  p = __builtin_amdgcn_cvt_pk_fp8_f32(c, d, p, true);
  return p;
}
__device__ __forceinline__ f32x2 unpk_lo(u32 v) {
  return __builtin_amdgcn_cvt_pk_f32_fp8(v, false);
}
__device__ __forceinline__ f32x2 unpk_hi(u32 v) {
  return __builtin_amdgcn_cvt_pk_f32_fp8(v, true);
}

#define GLD16(ldsptr, gptr)                                                     \
  __builtin_amdgcn_global_load_lds(                                             \
      (__attribute__((address_space(1))) void*)(gptr),                          \
      (__attribute__((address_space(3))) void*)(ldsptr), 16, 0, 0)

// ---------------------------------------------------------------------------
// reduce helpers
// ---------------------------------------------------------------------------
__device__ __forceinline__ float wave_red(float v) {
  for (int o = 32; o; o >>= 1) v += __shfl_down(v, o, 64);
  return v;
}

__device__ __forceinline__ float block_reduce1(float v) {
  __shared__ float buf[4];
  v = wave_red(v);
  int lane = threadIdx.x & 63, w = threadIdx.x >> 6;
  if (lane == 0) buf[w] = v;
  __syncthreads();
  float r = 0.f;
  if (threadIdx.x == 0) r = buf[0] + buf[1] + buf[2] + buf[3];
  return r;  // valid on thread 0
}

// ---------------------------------------------------------------------------
// fp32 -> fp8 (A only; scale 1)
// ---------------------------------------------------------------------------
__global__ void convert_f32_fp8(const float* __restrict__ in,
                                u8* __restrict__ out, int n4, float scale) {
  int i = blockIdx.x * blockDim.x + threadIdx.x;
  if (i < n4) {
    float4 v = ((const float4*)in)[i];
    ((u32*)out)[i] =
        pack4_fp8(v.x * scale, v.y * scale, v.z * scale, v.w * scale);
  }
}

// ---------------------------------------------------------------------------
// fused: W1/W2 fp32->fp8 (*WSCALE) + row norms + b1/b2 norms, all * E.
// ---------------------------------------------------------------------------
__global__ void prep_w(const float* __restrict__ W1,
                       const float* __restrict__ W2,
                       const float* __restrict__ b1,
                       const float* __restrict__ b2, u8* __restrict__ W1_8,
                       u8* __restrict__ W2_8, float* __restrict__ out) {
  const int blk = blockIdx.x;
  if (blk < H_DIM) {  // W1 row: 8192 floats
    const float4* row = (const float4*)(W1 + (size_t)blk * N_DIM);
    u32* orow = (u32*)(W1_8 + (size_t)blk * N_DIM);
    float s = 0.f;
#pragma unroll
    for (int t = 0; t < 8; ++t) {
      int i = threadIdx.x + t * 256;
      float4 v = row[i];
      s += v.x * v.x + v.y * v.y + v.z * v.z + v.w * v.w;
      orow[i] = pack4_fp8(v.x * WSCALE, v.y * WSCALE, v.z * WSCALE,
                          v.w * WSCALE);
    }
    s = block_reduce1(s);
    if (threadIdx.x == 0) atomicAdd(out, sqrtf(s) * (float)E_DIM);
  } else if (blk < H_DIM + N_DIM / 4) {  // W2: 4 rows/block, 1024 floats each
    __shared__ float buf[4];
    const int wave = threadIdx.x >> 6, lane = threadIdx.x & 63;
    const int r = (blk - H_DIM) * 4 + wave;
    const float4* row = (const float4*)(W2 + (size_t)r * H_DIM);
    u32* orow = (u32*)(W2_8 + (size_t)r * H_DIM);
    float s = 0.f;
#pragma unroll
    for (int t = 0; t < 4; ++t) {
      int i = lane + t * 64;
      float4 v = row[i];
      s += v.x * v.x + v.y * v.y + v.z * v.z + v.w * v.w;
      orow[i] = pack4_fp8(v.x * WSCALE, v.y * WSCALE, v.z * WSCALE,
                          v.w * WSCALE);
    }
    s = wave_red(s);
    if (lane == 0) buf[wave] = sqrtf(s);
    __syncthreads();
    if (threadIdx.x == 0)
      atomicAdd(out, (buf[0] + buf[1] + buf[2] + buf[3]) * (float)E_DIM);
  } else if (blk == H_DIM + N_DIM / 4) {  // ||b1||
    const float4* row = (const float4*)b1;
    float4 v = row[threadIdx.x];
    float s = v.x * v.x + v.y * v.y + v.z * v.z + v.w * v.w;
    s = block_reduce1(s);
    if (threadIdx.x == 0) atomicAdd(out, sqrtf(s) * (float)E_DIM);
  } else {  // ||b2||
    const float4* row = (const float4*)b2;
    float s = 0.f;
#pragma unroll
    for (int t = 0; t < 8; ++t) {
      float4 v = row[threadIdx.x + t * 256];
      s += v.x * v.x + v.y * v.y + v.z * v.z + v.w * v.w;
    }
    s = block_reduce1(s);
    if (threadIdx.x == 0) atomicAdd(out, sqrtf(s) * (float)E_DIM);
  }
}

// ---------------------------------------------------------------------------
// GEMM1: 128x128 tile, verified 2-barrier structure, + XCD-aware remap so
// each XCD owns contiguous row-panels (A L3 traffic 512->128 MB).
// C = fp8( WSCALE * sigmoid( invScale*(A B^T) + bias ) ), swapped MFMA.
// ---------------------------------------------------------------------------
#define BM 128
#define BN 128
#define BKB 128

__global__ __launch_bounds__(256) void gemm_fp8_sigmoid(
    const u8* __restrict__ Ag,    // [M][K]
    const u8* __restrict__ Bg,    // [Nd][K]
    const float* __restrict__ bias,
    u8* __restrict__ Cg,          // [M][Nd] e4m3, value*WSCALE
    float invScale, int K, int Nd) {
  __shared__ __align__(16) u8 Xs[BM * BKB];
  __shared__ __align__(16) u8 Ws[BN * BKB];

  // bijective XCD remap: XCD k gets contiguous chunk of flat ids (nwg%8==0)
  const int nwg = gridDim.x * gridDim.y;
  const int id = blockIdx.y * gridDim.x + blockIdx.x;
  const int wg = (id & 7) * (nwg >> 3) + (id >> 3);
  const int bx = wg % gridDim.x;
  const int by = wg / gridDim.x;

  const int tid = threadIdx.x;
  const int wave = tid >> 6, lane = tid & 63;
  const int wr = wave >> 1, wc = wave & 1;
  const size_t rowBase = (size_t)by * BM;
  const size_t colBase = (size_t)bx * BN;

  f32x4 acc[4][4] = {};

  const int i8 = lane >> 3;  // row within 8-row staging group
  const int c8 = lane & 7;   // LDS 16-B slot
  const int sw = c8 ^ i8;    // swizzled global 16-B unit

  const int quad = lane >> 4;
  const int m15 = lane & 15;

  for (int k0 = 0; k0 < K; k0 += BKB) {
#pragma unroll
    for (int j = 0; j < 4; ++j) {
      const int r0 = (wave * 4 + j) * 8;
      const u8* gx = Ag + (rowBase + r0 + i8) * (size_t)K + (k0 + sw * 16);
      GLD16(&Xs[r0 * BKB], gx);
      const u8* gw = Bg + (colBase + r0 + i8) * (size_t)K + (k0 + sw * 16);
      GLD16(&Ws[r0 * BKB], gw);
    }
    __syncthreads();

    i32x8 af[4], bfr[4];
#pragma unroll
    for (int t = 0; t < 4; ++t) {
      const int m = wr * 64 + t * 16 + m15;
      i32x4 alo = *(const i32x4*)&Xs[m * BKB + ((2 * quad) ^ (m & 7)) * 16];
      i32x4 ahi = *(const i32x4*)&Xs[m * BKB + ((2 * quad + 1) ^ (m & 7)) * 16];
      af[t] = __builtin_shufflevector(alo, ahi, 0, 1, 2, 3, 4, 5, 6, 7);
      const int n = wc * 64 + t * 16 + m15;
      i32x4 blo = *(const i32x4*)&Ws[n * BKB + ((2 * quad) ^ (n & 7)) * 16];
      i32x4 bhi = *(const i32x4*)&Ws[n * BKB + ((2 * quad + 1) ^ (n & 7)) * 16];
      bfr[t] = __builtin_shufflevector(blo, bhi, 0, 1, 2, 3, 4, 5, 6, 7);
    }
#pragma unroll
    for (int mt = 0; mt < 4; ++mt)
#pragma unroll
      for (int nt = 0; nt < 4; ++nt)
        acc[mt][nt] = __builtin_amdgcn_mfma_scale_f32_16x16x128_f8f6f4(
            bfr[nt], af[mt], acc[mt][nt], 0, 0,
            0, 0x7F7F7F7F, 0, 0x7F7F7F7F);  // SWAPPED: D[n][m] layout
    __syncthreads();
  }

  // epilogue: lane owns C row (mt*16+m15), cols nt*16+quad*4+{0..3}
  f32x4 bv4[4];
#pragma unroll
  for (int nt = 0; nt < 4; ++nt)
    bv4[nt] = *(const f32x4*)&bias[colBase + wc * 64 + nt * 16 + quad * 4];
#pragma unroll
  for (int mt = 0; mt < 4; ++mt) {
    const size_t grow = rowBase + wr * 64 + mt * 16 + m15;
    u32* crow = (u32*)(Cg + grow * (size_t)Nd + colBase + wc * 64);
#pragma unroll
    for (int nt = 0; nt < 4; ++nt) {
      float v[4];
#pragma unroll
      for (int i = 0; i < 4; ++i) {
        float x = acc[mt][nt][i] * invScale + bv4[nt][i];
        v[i] = WSCALE / (1.0f + __expf(-x));
      }
      crow[nt * 4 + quad] = pack4_fp8(v[0], v[1], v[2], v[3]);
    }
  }
}

// ---------------------------------------------------------------------------
// GEMM2: 256x256 tile, 8 waves (2x4), double-buffered LDS (128 KB), 1 blk/CU.
// Min-2-phase pipeline (T3): issue next K-tile's global_load_lds BEFORE
// computing the current tile; the single __syncthreads() per tile provides
// both the vmcnt(0) drain (loads were issued a full tile of MFMA earlier ->
// latency hidden) and the read-before-overwrite fence. Operands are
// L2/L3-resident (8 MB each) so 1-tile-deep prefetch suffices.
// ---------------------------------------------------------------------------
#define BM2 256
#define BN2 256

__global__ __launch_bounds__(512, 2) void gemm2_fp8_sigmoid(
    const u8* __restrict__ Ag,    // [M][K]  (H1)
    const u8* __restrict__ Bg,    // [Nd][K] (W2)
    const float* __restrict__ bias,
    u8* __restrict__ Cg,          // [M][Nd] e4m3, value*WSCALE
    float invScale, int K, int Nd) {
  __shared__ __align__(16) u8 Xs[2][BM2 * BKB];   // 2 x 32 KB
  __shared__ __align__(16) u8 Ws[2][BN2 * BKB];   // 2 x 32 KB

  const int tid = threadIdx.x;
  const int wave = tid >> 6, lane = tid & 63;
  const int wr = wave >> 2;          // 0..1 -> 128-row half
  const int wc = wave & 3;           // 0..3 -> 64-col quarter
  const size_t rowBase = (size_t)blockIdx.y * BM2;
  const size_t colBase = (size_t)blockIdx.x * BN2;

  f32x4 acc[8][4] = {};

  const int i8 = lane >> 3;
  const int c8 = lane & 7;
  const int sw = c8 ^ i8;            // swizzled global 16-B unit (key: row&7)
  const int quad = lane >> 4;
  const int m15 = lane & 15;

  const int T = K / BKB;

  // stage K-tile kt into buffer b: 8 gload_lds/thread-group, 256 rows each op
  auto STAGE = [&](int kt, int b) {
    const size_t kOff = (size_t)kt * BKB + sw * 16;
#pragma unroll
    for (int j = 0; j < 4; ++j) {
      const int r0 = (wave * 4 + j) * 8;  // 8 waves * 4 * 8 = 256 rows
      GLD16(&Xs[b][r0 * BKB], Ag + (rowBase + r0 + i8) * (size_t)K + kOff);
      GLD16(&Ws[b][r0 * BKB], Bg + (colBase + r0 + i8) * (size_t)K + kOff);
    }
  };

  STAGE(0, 0);
  __syncthreads();

  for (int t = 0; t < T; ++t) {
    const int cur = t & 1;
    if (t + 1 < T) STAGE(t + 1, cur ^ 1);  // in flight across this tile's MFMA

    const u8* Xb = Xs[cur];
    const u8* Wb = Ws[cur];

    i32x8 bfr[4];
#pragma unroll
    for (int nt = 0; nt < 4; ++nt) {
      const int n = wc * 64 + nt * 16 + m15;
      i32x4 blo = *(const i32x4*)&Wb[n * BKB + ((2 * quad) ^ (n & 7)) * 16];
      i32x4 bhi = *(const i32x4*)&Wb[n * BKB + ((2 * quad + 1) ^ (n & 7)) * 16];
      bfr[nt] = __builtin_shufflevector(blo, bhi, 0, 1, 2, 3, 4, 5, 6, 7);
    }
#pragma unroll
    for (int mt = 0; mt < 8; ++mt) {
      const int m = wr * 128 + mt * 16 + m15;
      i32x4 alo = *(const i32x4*)&Xb[m * BKB + ((2 * quad) ^ (m & 7)) * 16];
      i32x4 ahi = *(const i32x4*)&Xb[m * BKB + ((2 * quad + 1) ^ (m & 7)) * 16];
      i32x8 af = __builtin_shufflevector(alo, ahi, 0, 1, 2, 3, 4, 5, 6, 7);
#pragma unroll
      for (int nt = 0; nt < 4; ++nt)
        acc[mt][nt] = __builtin_amdgcn_mfma_scale_f32_16x16x128_f8f6f4(
            bfr[nt], af, acc[mt][nt], 0, 0,
            0, 0x7F7F7F7F, 0, 0x7F7F7F7F);  // SWAPPED: lane owns C-row m
    }
    __syncthreads();  // drains this wave's t+1 loads (issued ~1 tile ago) +
                      // fences all waves done reading buf[cur] before t+2
  }

  // epilogue: lane owns C row (wr*128+mt*16+m15), cols wc*64+nt*16+quad*4+i
  f32x4 bv4[4];
#pragma unroll
  for (int nt = 0; nt < 4; ++nt)
    bv4[nt] = *(const f32x4*)&bias[colBase + wc * 64 + nt * 16 + quad * 4];
#pragma unroll
  for (int mt = 0; mt < 8; ++mt) {
    const size_t grow = rowBase + wr * 128 + mt * 16 + m15;
    u32* crow = (u32*)(Cg + grow * (size_t)Nd + colBase + wc * 64);
#pragma unroll
    for (int nt = 0; nt < 4; ++nt) {
      float v[4];
#pragma unroll
      for (int i = 0; i < 4; ++i) {
        float x = acc[mt][nt][i] * invScale + bv4[nt][i];
        v[i] = WSCALE / (1.0f + __expf(-x));
      }
      crow[nt * 4 + quad] = pack4_fp8(v[0], v[1], v[2], v[3]);
    }
  }
}

// ---------------------------------------------------------------------------
// loss_1 layer-1: one WAVE per edge (4 edges/block); early-exit label==0.
// ---------------------------------------------------------------------------
__global__ void edge_loss_h(const u8* __restrict__ H1,
                            const int* __restrict__ edges,
                            const int* __restrict__ labels,
                            float* __restrict__ out) {
  __shared__ float buf[4];
  const int wave = threadIdx.x >> 6, lane = threadIdx.x & 63;
  const int e = blockIdx.x * 4 + wave;
  float r = 0.f;
  if (labels[e] != 0) {
    const int ni = edges[e * 2], nj = edges[e * 2 + 1];
    const i32x4 a = ((const i32x4*)(H1 + (size_t)ni * H_DIM))[lane];
    const i32x4 b = ((const i32x4*)(H1 + (size_t)nj * H_DIM))[lane];
    float s = 0.f;
#pragma unroll
    for (int j = 0; j < 4; ++j) {
      f32x2 al = unpk_lo((u32)a[j]), ah = unpk_hi((u32)a[j]);
      f32x2 bl = unpk_lo((u32)b[j]), bh = unpk_hi((u32)b[j]);
      float d0 = al.x - bl.x, d1 = al.y - bl.y;
      float d2 = ah.x - bh.x, d3 = ah.y - bh.y;
      s += d0 * d0 + d1 * d1 + d2 * d2 + d3 * d3;
    }
    s = wave_red(s);
    r = sqrtf(s) * INV_WSCALE;
  }
  if (lane == 0) buf[wave] = r;
  __syncthreads();
  if (threadIdx.x == 0) atomicAdd(out, buf[0] + buf[1] + buf[2] + buf[3]);
}

// ---------------------------------------------------------------------------
// loss_1 layer-2 + loss_2: one WAVE per edge, dwordx4 loads.
// ---------------------------------------------------------------------------
__global__ void edge_loss_final(const u8* __restrict__ H2,
                                const u8* __restrict__ A8,
                                const int* __restrict__ edges,
                                const int* __restrict__ labels,
                                float* __restrict__ out) {
  __shared__ float buf[4];
  const int wave = threadIdx.x >> 6, lane = threadIdx.x & 63;
  const int e = blockIdx.x * 4 + wave;
  const int ni = edges[e * 2], nj = edges[e * 2 + 1];
  const i32x4* hi = (const i32x4*)(H2 + (size_t)ni * N_DIM);
  const i32x4* hj = (const i32x4*)(H2 + (size_t)nj * N_DIM);
  const i32x4* xi = (const i32x4*)(A8 + (size_t)ni * N_DIM);
  const i32x4* xj = (const i32x4*)(A8 + (size_t)nj * N_DIM);
  float s12 = 0.f, si = 0.f, sj = 0.f;
#pragma unroll 2
  for (int t = 0; t < 8; ++t) {
    const int idx = lane + t * 64;
    i32x4 a = hi[idx], b = hj[idx], x = xi[idx], y = xj[idx];
#pragma unroll
    for (int j = 0; j < 4; ++j) {
      f32x2 al = unpk_lo((u32)a[j]), ah = unpk_hi((u32)a[j]);
      f32x2 bl = unpk_lo((u32)b[j]), bh = unpk_hi((u32)b[j]);
      f32x2 xl = unpk_lo((u32)x[j]), xh = unpk_hi((u32)x[j]);
      f32x2 yl = unpk_lo((u32)y[j]), yh = unpk_hi((u32)y[j]);
      float d;
      d = al.x - bl.x; s12 += d * d;
      d = al.y - bl.y; s12 += d * d;
      d = ah.x - bh.x; s12 += d * d;
      d = ah.y - bh.y; s12 += d * d;
      d = WSCALE * xl.x - al.x; si += d * d;
      d = WSCALE * xl.y - al.y; si += d * d;
      d = WSCALE * xh.x - ah.x; si += d * d;
      d = WSCALE * xh.y - ah.y; si += d * d;
      d = WSCALE * yl.x - bl.x; sj += d * d;
      d = WSCALE * yl.y - bl.y; sj += d * d;
      d = WSCALE * yh.x - bh.x; sj += d * d;
      d = WSCALE * yh.y - bh.y; sj += d * d;
    }
  }
  for (int o = 32; o; o >>= 1) {
    s12 += __shfl_down(s12, o, 64);
    si += __shfl_down(si, o, 64);
    sj += __shfl_down(sj, o, 64);
  }
  if (lane == 0) {
    float lab = (labels[e] != 0) ? 1.f : 0.f;
    float fac = (labels[e] != 0) ? PENALTY_F : 1.f;
    buf[wave] = (lab * sqrtf(s12) + fac * (sqrtf(si) + sqrtf(sj))) * INV_WSCALE;
  }
  __syncthreads();
  if (threadIdx.x == 0) atomicAdd(out, buf[0] + buf[1] + buf[2] + buf[3]);
}

// ---------------------------------------------------------------------------
extern "C" void kernel_launch(void* const* d_in, const int* in_sizes, int n_in,
                              void* d_out, int out_size, void* d_ws,
                              size_t ws_size, hipStream_t stream) {
  const float* A = (const float*)d_in[0];
  const float* W1 = (const float*)d_in[1];
  const float* b1 = (const float*)d_in[2];
  const float* W2 = (const float*)d_in[3];
  const float* b2 = (const float*)d_in[4];
  const int* edges = (const int*)d_in[5];
  const int* labels = (const int*)d_in[6];
  float* out = (float*)d_out;

  // workspace layout (bytes), total ~152 MB
  char* ws = (char*)d_ws;
  u8* A8   = (u8*)(ws);                       // N x N fp8     64 MB
  u8* H1_8 = (u8*)(ws + 67108864ull);         // N x H fp8      8 MB
  u8* H2_8 = (u8*)(ws + 75497472ull);         // N x N fp8     64 MB
  u8* W1_8 = (u8*)(ws + 142606336ull);        // H x N fp8      8 MB
  u8* W2_8 = (u8*)(ws + 150994944ull);        // N x H fp8      8 MB

  hipMemsetAsync(out, 0, sizeof(float), stream);

  // A -> fp8 (scale 1)
  convert_f32_fp8<<<(N_DIM * N_DIM / 4 + 255) / 256, 256, 0, stream>>>(
      A, A8, N_DIM * N_DIM / 4, 1.0f);

  // W1/W2 convert (*16) fused with row norms; b1/b2 norms; all *E, exact fp32
  prep_w<<<H_DIM + N_DIM / 4 + 2, 256, 0, stream>>>(W1, W2, b1, b2, W1_8,
                                                    W2_8, out);

  // layer 1 (per node): H1 = sigmoid(A @ W1^T + b1)   [N x H]  128^2 tiles
  gemm_fp8_sigmoid<<<dim3(H_DIM / BN, N_DIM / BM), 256, 0, stream>>>(
      A8, W1_8, b1, H1_8, INV_WSCALE, N_DIM, H_DIM);
  edge_loss_h<<<E_DIM / 4, 256, 0, stream>>>(H1_8, edges, labels, out);

  // layer 2 (per node): H2 = sigmoid(H1 @ W2^T + b2)  [N x N]  256^2 pipelined
  gemm2_fp8_sigmoid<<<dim3(N_DIM / BN2, N_DIM / BM2), 512, 0, stream>>>(
      H1_8, W2_8, b2, H2_8, INV_WSCALE * INV_WSCALE, H_DIM, N_DIM);
  edge_loss_final<<<E_DIM / 4, 256, 0, stream>>>(H2_8, A8, edges, labels, out);
}